// Round 1
// baseline (312.317 us; speedup 1.0000x reference)
//
#include <hip/hip_runtime.h>
#include <cmath>

#define NUM_POS 10
#define NEG 1000
#define COLS 1010          // NUM_POS + NEG
#define BATCH 4096
#define USERS 10001
#define ITEMS 10001
#define R_TOT (BATCH * NUM_POS)   // 40960
#define HSIZE (1 << 17)
#define GAMMA0 0.1f
#define EPSV 1e-10f

// ---------------- kernel 1: per-row max(neg) - min(pos) ----------------
__global__ void k_rowstat(const float* __restrict__ pred, float* __restrict__ rowM) {
    int b = blockIdx.x;
    const float* row = pred + (size_t)b * COLS;
    float mn = INFINITY, mx = -INFINITY;
    for (int c = threadIdx.x; c < COLS; c += 256) {
        float v = row[c];
        if (c < NUM_POS) mn = fminf(mn, v);
        else             mx = fmaxf(mx, v);
    }
    __shared__ float smn[4], smx[4];
    int lane = threadIdx.x & 63, wid = threadIdx.x >> 6;
    for (int off = 32; off; off >>= 1) {
        mn = fminf(mn, __shfl_down(mn, off));
        mx = fmaxf(mx, __shfl_down(mx, off));
    }
    if (lane == 0) { smn[wid] = mn; smx[wid] = mx; }
    __syncthreads();
    if (threadIdx.x == 0) {
        mn = fminf(fminf(smn[0], smn[1]), fminf(smn[2], smn[3]));
        mx = fmaxf(fmaxf(smx[0], smx[1]), fmaxf(smx[2], smx[3]));
        rowM[b] = mx - mn;   // max over p,j of margin within row b
    }
}

// ---------------- kernel 2: global max over 4096 row maxima ----------------
__global__ void k_gmax(const float* __restrict__ rowM, float* __restrict__ Mout) {
    float mx = -INFINITY;
    for (int i = threadIdx.x; i < BATCH; i += 256) mx = fmaxf(mx, rowM[i]);
    __shared__ float smx[4];
    int lane = threadIdx.x & 63, wid = threadIdx.x >> 6;
    for (int off = 32; off; off >>= 1) mx = fmaxf(mx, __shfl_down(mx, off));
    if (lane == 0) smx[wid] = mx;
    __syncthreads();
    if (threadIdx.x == 0)
        Mout[0] = fmaxf(fmaxf(smx[0], smx[1]), fmaxf(smx[2], smx[3]));
}

// -------- kernel 3: per-row E,F sums; emit meanexp/sumS/keys per (b,p) --------
__global__ void k_rowsums(const float* __restrict__ pred, const float* __restrict__ Mptr,
                          const int* __restrict__ user_id, const int* __restrict__ item_id,
                          float* __restrict__ meanexp, float* __restrict__ sumS,
                          int* __restrict__ keys) {
    int b = blockIdx.x;
    float M = Mptr[0];
    const float* row = pred + (size_t)b * COLS;
    float e = 0.f, f = 0.f;
    for (int c = NUM_POS + threadIdx.x; c < COLS; c += 256) {
        float v = row[c];
        float w = expf(v - M);
        e += w; f += v * w;
    }
    __shared__ float sh[8], bc[2];
    int lane = threadIdx.x & 63, wid = threadIdx.x >> 6;
    for (int off = 32; off; off >>= 1) { e += __shfl_down(e, off); f += __shfl_down(f, off); }
    if (lane == 0) { sh[wid] = e; sh[4 + wid] = f; }
    __syncthreads();
    if (threadIdx.x == 0) {
        bc[0] = (sh[0] + sh[1]) + (sh[2] + sh[3]);
        bc[1] = (sh[4] + sh[5]) + (sh[6] + sh[7]);
    }
    __syncthreads();
    if (threadIdx.x < NUM_POS) {
        float E = bc[0], F = bc[1];
        int p = threadIdx.x;
        int r = b * NUM_POS + p;
        float pos = row[p];
        float s = expf(-pos);
        // sum_j exp(neg_j - pos - M) = exp(-pos) * E ; mean over NEG
        meanexp[r] = s * E * (1.0f / NEG);
        // sum_j (neg_j - pos) * exp(neg_j - pos - M) = exp(-pos)*(F - pos*E)
        sumS[r]    = s * (F - pos * E);
        keys[r]    = user_id[b] * ITEMS + item_id[r];
    }
}

// -------- kernel 4: hash-insert keys, winner = max r per key (last write wins) --------
__device__ __forceinline__ unsigned hash_key(int k) {
    return (((unsigned)k * 2654435761u) >> 13) & (HSIZE - 1);
}

__global__ void k_insert(const int* __restrict__ keys, int* __restrict__ hkey,
                         int* __restrict__ hval) {
    int r = blockIdx.x * 256 + threadIdx.x;
    if (r >= R_TOT) return;
    int k = keys[r];
    unsigned s = hash_key(k);
    while (true) {
        int old = atomicCAS(&hkey[s], -1, k);
        if (old == -1 || old == k) { atomicMax(&hval[s], r); break; }
        s = (s + 1) & (HSIZE - 1);
    }
}

// -------- kernel 5: scatter winners into u_out, accumulate loss partials --------
__global__ void k_scatter_loss(const float* __restrict__ u_in,
                               const float* __restrict__ meanexp,
                               const float* __restrict__ sumS,
                               const int* __restrict__ keys,
                               const int* __restrict__ hkey, const int* __restrict__ hval,
                               float* __restrict__ u_out, float* __restrict__ partial) {
    int r = blockIdx.x * 256 + threadIdx.x;
    int k = keys[r];
    unsigned s = hash_key(k);
    while (hkey[s] != k) s = (s + 1) & (HSIZE - 1);
    int win = hval[s];                       // last duplicate index wins
    float uval = u_in[(size_t)k];            // pre-scatter value (same cell for all dups)
    float nv = (1.0f - GAMMA0) * uval + GAMMA0 * meanexp[win];
    if (win == r) u_out[(size_t)k] = nv;     // the single winning write
    float contrib = sumS[r] / (nv + EPSV);   // gather-after-scatter value

    __shared__ float sh[4];
    int lane = threadIdx.x & 63, wid = threadIdx.x >> 6;
    for (int off = 32; off; off >>= 1) contrib += __shfl_down(contrib, off);
    if (lane == 0) sh[wid] = contrib;
    __syncthreads();
    if (threadIdx.x == 0)
        partial[blockIdx.x] = (sh[0] + sh[1]) + (sh[2] + sh[3]);
}

// ---------------- kernel 6: final loss reduce ----------------
__global__ void k_final(const float* __restrict__ partial, float* __restrict__ out) {
    float v = (threadIdx.x < R_TOT / 256) ? partial[threadIdx.x] : 0.0f;
    __shared__ float sh[4];
    int lane = threadIdx.x & 63, wid = threadIdx.x >> 6;
    for (int off = 32; off; off >>= 1) v += __shfl_down(v, off);
    if (lane == 0) sh[wid] = v;
    __syncthreads();
    if (threadIdx.x == 0)
        out[0] = ((sh[0] + sh[1]) + (sh[2] + sh[3])) * (1.0f / BATCH);
}

extern "C" void kernel_launch(void* const* d_in, const int* in_sizes, int n_in,
                              void* d_out, int out_size, void* d_ws, size_t ws_size,
                              hipStream_t stream) {
    const float* pred    = (const float*)d_in[0];   // (4096, 1010)
    const float* u       = (const float*)d_in[1];   // (10001, 10001)
    const int*   user_id = (const int*)d_in[2];     // (4096,)
    const int*   item_id = (const int*)d_in[3];     // (4096, 10) flat

    float* out   = (float*)d_out;   // [0] = loss, [1..] = u_new
    float* u_out = out + 1;

    char* w = (char*)d_ws;
    float* rowM    = (float*)w;  w += BATCH * sizeof(float);
    float* Mptr    = (float*)w;  w += 64;
    float* meanexp = (float*)w;  w += R_TOT * sizeof(float);
    float* sumS    = (float*)w;  w += R_TOT * sizeof(float);
    int*   keys    = (int*)w;    w += R_TOT * sizeof(int);
    int*   hkey    = (int*)w;    w += HSIZE * sizeof(int);
    int*   hval    = (int*)w;    w += HSIZE * sizeof(int);
    float* partial = (float*)w;  w += 256 * sizeof(float);

    // Bulk copy u -> u_new region (the 400 MB floor); scatter overwrites later.
    hipMemcpyAsync(u_out, u, (size_t)USERS * ITEMS * sizeof(float),
                   hipMemcpyDeviceToDevice, stream);
    hipMemsetAsync(hkey, 0xFF, HSIZE * sizeof(int), stream);   // -1 = empty
    hipMemsetAsync(hval, 0x00, HSIZE * sizeof(int), stream);

    k_rowstat<<<BATCH, 256, 0, stream>>>(pred, rowM);
    k_gmax<<<1, 256, 0, stream>>>(rowM, Mptr);
    k_rowsums<<<BATCH, 256, 0, stream>>>(pred, Mptr, user_id, item_id, meanexp, sumS, keys);
    k_insert<<<R_TOT / 256, 256, 0, stream>>>(keys, hkey, hval);
    k_scatter_loss<<<R_TOT / 256, 256, 0, stream>>>(u, meanexp, sumS, keys, hkey, hval,
                                                    u_out, partial);
    k_final<<<1, 256, 0, stream>>>(partial, out);
}

// Round 2
// 211.284 us; speedup vs baseline: 1.4782x; 1.4782x over previous
//
#include <hip/hip_runtime.h>
#include <cmath>

#define NUM_POS 10
#define NEG 1000
#define COLS 1010          // NUM_POS + NEG
#define BATCH 4096
#define USERS 10001
#define ITEMS 10001
#define R_TOT (BATCH * NUM_POS)   // 40960
#define HSIZE (1 << 17)
#define GAMMA0 0.1f
#define EPSV 1e-10f

#define N_U 100020001LL            // USERS*ITEMS elements in u
// out[0]=loss, out[1..N_U]=u_new.  Quads on out's 16B grid: out4[k]=out[4k..4k+3]
// valid full quads: k = 1 .. 25004999  (out[4..100019999])
#define KMAX 25005000LL

// ---------------- copy kernel: out[4k..4k+3] = u[4k-1..4k+2] ----------------
__global__ void k_copy(const float* __restrict__ u, float* __restrict__ out) {
    long long stride = (long long)gridDim.x * blockDim.x;
    long long k0 = 1 + (long long)blockIdx.x * blockDim.x + threadIdx.x;
    for (long long k = k0; k < KMAX; k += stride) {
        float4 a = ((const float4*)u)[k];          // u[4k..4k+3], 16B aligned
        float prev = __shfl_up(a.w, 1);            // u[4(k-1)+3] = u[4k-1]
        if ((threadIdx.x & 63) == 0) prev = u[4 * k - 1];
        float4 o;
        o.x = prev; o.y = a.x; o.z = a.y; o.w = a.z;
        ((float4*)out)[k] = o;                     // 16B aligned store
    }
    if (blockIdx.x == 0 && threadIdx.x == 0) {
        // head: out[1..3] = u[0..2]; tail: out[100020000..100020001] = u[100019999..100020000]
        out[1] = u[0]; out[2] = u[1]; out[3] = u[2];
        out[100020000] = u[100019999];
        out[100020001] = u[100020000];
    }
}

// ---------------- kernel 1: per-row max(neg) - min(pos) ----------------
__global__ void k_rowstat(const float* __restrict__ pred, float* __restrict__ rowM) {
    int b = blockIdx.x;
    const float* row = pred + (size_t)b * COLS;
    float mn = INFINITY, mx = -INFINITY;
    for (int c = threadIdx.x; c < COLS; c += 256) {
        float v = row[c];
        if (c < NUM_POS) mn = fminf(mn, v);
        else             mx = fmaxf(mx, v);
    }
    __shared__ float smn[4], smx[4];
    int lane = threadIdx.x & 63, wid = threadIdx.x >> 6;
    for (int off = 32; off; off >>= 1) {
        mn = fminf(mn, __shfl_down(mn, off));
        mx = fmaxf(mx, __shfl_down(mx, off));
    }
    if (lane == 0) { smn[wid] = mn; smx[wid] = mx; }
    __syncthreads();
    if (threadIdx.x == 0) {
        mn = fminf(fminf(smn[0], smn[1]), fminf(smn[2], smn[3]));
        mx = fmaxf(fmaxf(smx[0], smx[1]), fmaxf(smx[2], smx[3]));
        rowM[b] = mx - mn;   // max over p,j of margin within row b
    }
}

// ---------------- kernel 2: global max over 4096 row maxima ----------------
__global__ void k_gmax(const float* __restrict__ rowM, float* __restrict__ Mout) {
    float mx = -INFINITY;
    for (int i = threadIdx.x; i < BATCH; i += 256) mx = fmaxf(mx, rowM[i]);
    __shared__ float smx[4];
    int lane = threadIdx.x & 63, wid = threadIdx.x >> 6;
    for (int off = 32; off; off >>= 1) mx = fmaxf(mx, __shfl_down(mx, off));
    if (lane == 0) smx[wid] = mx;
    __syncthreads();
    if (threadIdx.x == 0)
        Mout[0] = fmaxf(fmaxf(smx[0], smx[1]), fmaxf(smx[2], smx[3]));
}

// -------- kernel 3: per-row E,F sums; emit meanexp/sumS/keys per (b,p) --------
__global__ void k_rowsums(const float* __restrict__ pred, const float* __restrict__ Mptr,
                          const int* __restrict__ user_id, const int* __restrict__ item_id,
                          float* __restrict__ meanexp, float* __restrict__ sumS,
                          int* __restrict__ keys) {
    int b = blockIdx.x;
    float M = Mptr[0];
    const float* row = pred + (size_t)b * COLS;
    float e = 0.f, f = 0.f;
    for (int c = NUM_POS + threadIdx.x; c < COLS; c += 256) {
        float v = row[c];
        float w = expf(v - M);
        e += w; f += v * w;
    }
    __shared__ float sh[8], bc[2];
    int lane = threadIdx.x & 63, wid = threadIdx.x >> 6;
    for (int off = 32; off; off >>= 1) { e += __shfl_down(e, off); f += __shfl_down(f, off); }
    if (lane == 0) { sh[wid] = e; sh[4 + wid] = f; }
    __syncthreads();
    if (threadIdx.x == 0) {
        bc[0] = (sh[0] + sh[1]) + (sh[2] + sh[3]);
        bc[1] = (sh[4] + sh[5]) + (sh[6] + sh[7]);
    }
    __syncthreads();
    if (threadIdx.x < NUM_POS) {
        float E = bc[0], F = bc[1];
        int p = threadIdx.x;
        int r = b * NUM_POS + p;
        float pos = row[p];
        float s = expf(-pos);
        meanexp[r] = s * E * (1.0f / NEG);
        sumS[r]    = s * (F - pos * E);
        keys[r]    = user_id[b] * ITEMS + item_id[r];
    }
}

// -------- kernel 4: hash-insert keys, winner = max r per key (last write wins) --------
__device__ __forceinline__ unsigned hash_key(int k) {
    return (((unsigned)k * 2654435761u) >> 13) & (HSIZE - 1);
}

__global__ void k_insert(const int* __restrict__ keys, int* __restrict__ hkey,
                         int* __restrict__ hval) {
    int r = blockIdx.x * 256 + threadIdx.x;
    if (r >= R_TOT) return;
    int k = keys[r];
    unsigned s = hash_key(k);
    while (true) {
        int old = atomicCAS(&hkey[s], -1, k);
        if (old == -1 || old == k) { atomicMax(&hval[s], r); break; }
        s = (s + 1) & (HSIZE - 1);
    }
}

// -------- kernel 5: scatter winners into u_out, accumulate loss partials --------
__global__ void k_scatter_loss(const float* __restrict__ u_in,
                               const float* __restrict__ meanexp,
                               const float* __restrict__ sumS,
                               const int* __restrict__ keys,
                               const int* __restrict__ hkey, const int* __restrict__ hval,
                               float* __restrict__ u_out, float* __restrict__ partial) {
    int r = blockIdx.x * 256 + threadIdx.x;
    int k = keys[r];
    unsigned s = hash_key(k);
    while (hkey[s] != k) s = (s + 1) & (HSIZE - 1);
    int win = hval[s];                       // last duplicate index wins
    float uval = u_in[(size_t)k];            // pre-scatter value (same cell for all dups)
    float nv = (1.0f - GAMMA0) * uval + GAMMA0 * meanexp[win];
    if (win == r) u_out[(size_t)k] = nv;     // the single winning write
    float contrib = sumS[r] / (nv + EPSV);   // gather-after-scatter value

    __shared__ float sh[4];
    int lane = threadIdx.x & 63, wid = threadIdx.x >> 6;
    for (int off = 32; off; off >>= 1) contrib += __shfl_down(contrib, off);
    if (lane == 0) sh[wid] = contrib;
    __syncthreads();
    if (threadIdx.x == 0)
        partial[blockIdx.x] = (sh[0] + sh[1]) + (sh[2] + sh[3]);
}

// ---------------- kernel 6: final loss reduce ----------------
__global__ void k_final(const float* __restrict__ partial, float* __restrict__ out) {
    float v = (threadIdx.x < R_TOT / 256) ? partial[threadIdx.x] : 0.0f;
    __shared__ float sh[4];
    int lane = threadIdx.x & 63, wid = threadIdx.x >> 6;
    for (int off = 32; off; off >>= 1) v += __shfl_down(v, off);
    if (lane == 0) sh[wid] = v;
    __syncthreads();
    if (threadIdx.x == 0)
        out[0] = ((sh[0] + sh[1]) + (sh[2] + sh[3])) * (1.0f / BATCH);
}

extern "C" void kernel_launch(void* const* d_in, const int* in_sizes, int n_in,
                              void* d_out, int out_size, void* d_ws, size_t ws_size,
                              hipStream_t stream) {
    const float* pred    = (const float*)d_in[0];   // (4096, 1010)
    const float* u       = (const float*)d_in[1];   // (10001, 10001)
    const int*   user_id = (const int*)d_in[2];     // (4096,)
    const int*   item_id = (const int*)d_in[3];     // (4096, 10) flat

    float* out   = (float*)d_out;   // [0] = loss, [1..] = u_new
    float* u_out = out + 1;

    char* w = (char*)d_ws;
    float* rowM    = (float*)w;  w += BATCH * sizeof(float);
    float* Mptr    = (float*)w;  w += 64;
    float* meanexp = (float*)w;  w += R_TOT * sizeof(float);
    float* sumS    = (float*)w;  w += R_TOT * sizeof(float);
    int*   keys    = (int*)w;    w += R_TOT * sizeof(int);
    int*   hkey    = (int*)w;    w += HSIZE * sizeof(int);
    int*   hval    = (int*)w;    w += HSIZE * sizeof(int);
    float* partial = (float*)w;  w += 256 * sizeof(float);

    hipMemsetAsync(hkey, 0xFF, HSIZE * sizeof(int), stream);   // -1 = empty
    hipMemsetAsync(hval, 0x00, HSIZE * sizeof(int), stream);

    k_rowstat<<<BATCH, 256, 0, stream>>>(pred, rowM);
    k_gmax<<<1, 256, 0, stream>>>(rowM, Mptr);
    k_rowsums<<<BATCH, 256, 0, stream>>>(pred, Mptr, user_id, item_id, meanexp, sumS, keys);
    k_insert<<<R_TOT / 256, 256, 0, stream>>>(keys, hkey, hval);

    // Bulk copy u -> u_new (custom float4 copy; the 800 MB HBM floor)
    k_copy<<<2048, 256, 0, stream>>>(u, out);

    k_scatter_loss<<<R_TOT / 256, 256, 0, stream>>>(u, meanexp, sumS, keys, hkey, hval,
                                                    u_out, partial);
    k_final<<<1, 256, 0, stream>>>(partial, out);
}